// Round 9
// baseline (425.167 us; speedup 1.0000x reference)
//
#include <hip/hip_runtime.h>

#define H_IMG 1024
#define W_IMG 1024
#define N_IMG 16
#define C_IMG 3

// Output tile per block: TW x TH px, 256 threads, 2 px/thread.
#define TW 32
#define TH 16
// Staged input region budget (floats). 48*32*4B*3ch = 18 KB -> 8 blocks/CU.
#define LX 48
#define LY 32

__global__ __launch_bounds__(256) void homography_warp_kernel(
    const float* __restrict__ img,   // [N, 3, H, W]
    const float* __restrict__ homo,  // [N, 3, 3]
    float* __restrict__ out)         // [N, 3, H, W]
{
    __shared__ float smem[C_IMG][LY][LX];

    const int n   = blockIdx.y;
    const int pbx = blockIdx.x;                           // XCD = pbx % 8
    const int lbx = (pbx & 7) * (2048 / 8) + (pbx >> 3);  // band-contiguous logical id
    const int tile_r = lbx >> 5;          // 0..63  (row tile)
    const int tile_c = lbx & 31;          // 0..31  (col tile)
    const int c0 = tile_c * TW;
    const int r0 = tile_r * TH;

    const int tid  = threadIdx.x;
    const int col  = c0 + (tid & 31);
    const int row0 = r0 + (tid >> 5);     // handles row0 and row0 + TH/2

    const float* Hm = homo + n * 9;
    const float h00 = Hm[0], h01 = Hm[1], h02 = Hm[2];
    const float h10 = Hm[3], h11 = Hm[4], h12 = Hm[5];
    const float h20 = Hm[6], h21 = Hm[7], h22 = Hm[8];

    const size_t plane = (size_t)H_IMG * W_IMG;
    const size_t base  = (size_t)n * C_IMG * plane;

    // ---- block-uniform input-region bounds from the 4 tile corners --------
    // A homography maps straight lines to straight lines, so the input
    // footprint of the output-tile rectangle is bounded by its corner images
    // (tz ~ 1 here, no sign change). +-1 px margin covers fp differences.
    float xmn = 1e30f, xmx = -1e30f, ymn = 1e30f, ymx = -1e30f;
#pragma unroll
    for (int k = 0; k < 4; ++k) {
        const float gxc = fmaf((float)((k & 1) ? (c0 + TW - 1) : c0), 2.0f / (W_IMG - 1), -1.0f);
        const float gyc = fmaf((float)((k & 2) ? (r0 + TH - 1) : r0), 2.0f / (H_IMG - 1), -1.0f);
        const float txc = fmaf(h00, gxc, fmaf(h01, gyc, h02));
        const float tyc = fmaf(h10, gxc, fmaf(h11, gyc, h12));
        const float tzc = fmaf(h20, gxc, fmaf(h21, gyc, h22));
        float ivc = __builtin_amdgcn_rcpf(tzc);
        ivc = ivc * (2.0f - tzc * ivc);
        const float xc = (txc * ivc + 1.0f) * 0.5f * (float)(W_IMG - 1);
        const float yc = (tyc * ivc + 1.0f) * 0.5f * (float)(H_IMG - 1);
        xmn = fminf(xmn, xc); xmx = fmaxf(xmx, xc);
        ymn = fminf(ymn, yc); ymx = fmaxf(ymx, yc);
    }
    const int xmin = (int)floorf(xmn - 1.0f);
    const int xmax = (int)floorf(xmx + 1.0f);
    const int ymin = (int)floorf(ymn - 1.0f);
    const int ymax = (int)floorf(ymx + 1.0f);

    // Staged window [sy0..sy1] x [sx0..sx1]; clamped per-lane indices are
    // contained in it by monotonicity of clamp (see weights: OOB corners
    // carry weight 0, so clamped reads are exact).
    const int sx0 = min(max(xmin, 0), W_IMG - 2);
    const int sx1 = min(max(xmax + 1, sx0 + 1), W_IMG - 1);
    const int sy0 = min(max(ymin, 0), H_IMG - 1);
    const int sy1 = min(max(ymax + 1, sy0), H_IMG - 1);
    const int spanx = sx1 - sx0 + 1;
    const int spany = sy1 - sy0 + 1;

    const bool fast = (spanx <= LX) && (spany <= LY);   // block-uniform

    if (fast) {
        // ---- stage region into LDS (coalesced row-segment loads) ----------
        const int total = spany * LX;
#pragma unroll
        for (int ch = 0; ch < C_IMG; ++ch) {
            const float* pc = img + base + (size_t)ch * plane;
            for (int i = tid; i < total; i += 256) {
                const int ly = i / LX;            // compile-time divisor -> magic mul
                const int lx = i - ly * LX;
                if (lx < spanx)
                    smem[ch][ly][lx] = pc[(sy0 + ly) * W_IMG + sx0 + lx];
            }
        }
        __syncthreads();
    }

#pragma unroll
    for (int g = 0; g < 2; ++g) {
        const int row = row0 + g * (TH / 2);
        const int pix = row * W_IMG + col;

        const float gx = fmaf((float)col, 2.0f / (W_IMG - 1), -1.0f);
        const float gy = fmaf((float)row, 2.0f / (H_IMG - 1), -1.0f);

        const float tx = fmaf(h00, gx, fmaf(h01, gy, h02));
        const float ty = fmaf(h10, gx, fmaf(h11, gy, h12));
        const float tz = fmaf(h20, gx, fmaf(h21, gy, h22));
        float inv = __builtin_amdgcn_rcpf(tz);
        inv = inv * (2.0f - tz * inv);             // ~1 ulp, err << tolerance
        const float u = tx * inv;
        const float v = ty * inv;

        const float xp = (u + 1.0f) * 0.5f * (float)(W_IMG - 1);
        const float yp = (v + 1.0f) * 0.5f * (float)(H_IMG - 1);

        const float x0f = floorf(xp);
        const float y0f = floorf(yp);
        const float fx = xp - x0f;
        const float fy = yp - y0f;

        const int ix0 = (int)x0f;
        const int iy0 = (int)y0f;
        const int ix1 = ix0 + 1;
        const int iy1 = iy0 + 1;

        const float vx0 = (ix0 >= 0 && ix0 < W_IMG) ? 1.0f : 0.0f;
        const float vx1 = (ix1 >= 0 && ix1 < W_IMG) ? 1.0f : 0.0f;
        const float vy0 = (iy0 >= 0 && iy0 < H_IMG) ? 1.0f : 0.0f;
        const float vy1 = (iy1 >= 0 && iy1 < H_IMG) ? 1.0f : 0.0f;

        const float w00 = (1.0f - fx) * (1.0f - fy) * vx0 * vy0;
        const float w01 = fx * (1.0f - fy) * vx1 * vy0;
        const float w10 = (1.0f - fx) * fy * vx0 * vy1;
        const float w11 = fx * fy * vx1 * vy1;

        const int cx0 = min(max(ix0, 0), W_IMG - 1);
        const int cx1 = min(max(ix1, 0), W_IMG - 1);
        const int cy0 = min(max(iy0, 0), H_IMG - 1);
        const int cy1 = min(max(iy1, 0), H_IMG - 1);

        float r[C_IMG];
        if (fast) {
            const int lx0 = cx0 - sx0, lx1 = cx1 - sx0;
            const int ly0 = cy0 - sy0, ly1 = cy1 - sy0;
#pragma unroll
            for (int ch = 0; ch < C_IMG; ++ch) {
                const float v00 = smem[ch][ly0][lx0];
                const float v01 = smem[ch][ly0][lx1];
                const float v10 = smem[ch][ly1][lx0];
                const float v11 = smem[ch][ly1][lx1];
                r[ch] = w00 * v00 + w01 * v01 + w10 * v10 + w11 * v11;
            }
        } else {
            const int o00 = cy0 * W_IMG + cx0;
            const int o01 = cy0 * W_IMG + cx1;
            const int o10 = cy1 * W_IMG + cx0;
            const int o11 = cy1 * W_IMG + cx1;
#pragma unroll
            for (int ch = 0; ch < C_IMG; ++ch) {
                const float* p = img + base + (size_t)ch * plane;
                r[ch] = w00 * p[o00] + w01 * p[o01] + w10 * p[o10] + w11 * p[o11];
            }
        }

#pragma unroll
        for (int ch = 0; ch < C_IMG; ++ch)
            out[base + (size_t)ch * plane + (size_t)pix] = r[ch];
    }
}

extern "C" void kernel_launch(void* const* d_in, const int* in_sizes, int n_in,
                              void* d_out, int out_size, void* d_ws, size_t ws_size,
                              hipStream_t stream) {
    const float* img  = (const float*)d_in[0];   // patch_src    [16,3,1024,1024]
    const float* homo = (const float*)d_in[1];   // dst_homo_src [16,3,3]
    float* out = (float*)d_out;                  // [16,3,1024,1024] fp32

    dim3 block(256);
    dim3 grid((W_IMG / TW) * (H_IMG / TH), N_IMG);   // 2048 tiles/image
    homography_warp_kernel<<<grid, block, 0, stream>>>(img, homo, out);
}